// Round 2
// baseline (2018.548 us; speedup 1.0000x reference)
//
#include <hip/hip_runtime.h>
#include <cstdint>
#include <cstddef>

// CP_TransformerDecoder on MI355X — round 1 resubmit (infra failure last round):
// correctness-first bf16 MFMA pipeline + wave-race hardening in attn (barrier
// between P-store and PV-read).
// All CP adapter paths folded into precomputed P-matrices (rank-64 weight-space GEMMs),
// then: per layer LN -> u-proj -> adapter GEMM -> qkv GEMM(+scatter) -> flash attn ->
// proj(+resid) -> LN2 -> fc1(+GELU) -> u4 -> fc2(+resid).

typedef __bf16 bf16_t;
typedef __bf16 bf16x8 __attribute__((ext_vector_type(8)));
typedef float  f32x4  __attribute__((ext_vector_type(4)));

#define DEVI __device__ __forceinline__

DEVI f32x4 mfma16(bf16x8 a, bf16x8 b, f32x4 c) {
  return __builtin_amdgcn_mfma_f32_16x16x32_bf16(a, b, c, 0, 0, 0);
}

DEVI void async16(const void* g, void* l) {
  __builtin_amdgcn_global_load_lds((const __attribute__((address_space(1))) void*)g,
                                   (__attribute__((address_space(3))) void*)l, 16, 0, 0);
}

DEVI float gelu_f(float v) { return 0.5f * v * (1.0f + erff(v * 0.70710678118654752440f)); }

// ---------------- elementwise / preprocessing kernels ----------------

__global__ __launch_bounds__(256) void convert_kernel(const float* __restrict__ src,
                                                      bf16_t* __restrict__ dst, int n4) {
  int i = blockIdx.x * 256 + threadIdx.x;
  if (i >= n4) return;
  float4 v = ((const float4*)src)[i];
  union { bf16_t o[4]; uint2 u; } pk;
  pk.o[0] = (bf16_t)v.x; pk.o[1] = (bf16_t)v.y; pk.o[2] = (bf16_t)v.z; pk.o[3] = (bf16_t)v.w;
  ((uint2*)dst)[i] = pk.u;
}

// convert one layer's {qkv, proj, fc1, fc2} fp32 weights into one bf16 buffer
__global__ __launch_bounds__(256) void convert_w_kernel(const float* __restrict__ s0,
    const float* __restrict__ s1, const float* __restrict__ s2, const float* __restrict__ s3,
    bf16_t* __restrict__ dst) {
  size_t i = ((size_t)blockIdx.x * 256 + threadIdx.x) * 4;  // 12582912 total elems
  const float* src; size_t off;
  if (i < 3145728)      { src = s0; off = i; }
  else if (i < 4194304) { src = s1; off = i - 3145728; }
  else if (i < 8388608) { src = s2; off = i - 4194304; }
  else                  { src = s3; off = i - 8388608; }
  float4 v = *(const float4*)(src + off);
  union { bf16_t o[4]; uint2 u; } pk;
  pk.o[0] = (bf16_t)v.x; pk.o[1] = (bf16_t)v.y; pk.o[2] = (bf16_t)v.z; pk.o[3] = (bf16_t)v.w;
  *(uint2*)(dst + i) = pk.u;
}

// CPcat[l][r1][r2][f], f=0..3 from cp_att, f=4..11 from mlp_cp
__global__ __launch_bounds__(256) void cpcat_kernel(const float* __restrict__ cp_c,
    const float* __restrict__ cp_att, const float* __restrict__ mlp_cp, float* __restrict__ cpcat) {
  int idx = blockIdx.x * 256 + threadIdx.x;  // 16384 = L*64*64
  int lay = idx >> 12, ab = idx & 4095;
  const float* crow = cp_c + (size_t)ab * 64;
  float acc[12];
#pragma unroll
  for (int f = 0; f < 12; ++f) acc[f] = 0.f;
  for (int r = 0; r < 64; ++r) {
    float cv = crow[r];
    const float* wa = cp_att + lay * 256 + r * 4;
    const float* wm = mlp_cp + lay * 512 + r * 8;
#pragma unroll
    for (int f = 0; f < 4; ++f) acc[f] += cv * wa[f];
#pragma unroll
    for (int f = 0; f < 8; ++f) acc[4 + f] += cv * wm[f];
  }
  float* o = cpcat + (size_t)idx * 12;
#pragma unroll
  for (int f = 0; f < 12; ++f) o[f] = acc[f];
}

// Wp_att[l][f][cout][r1] = sum_r2 CPcat[l][r1][r2][f] * v_w[cout][r2]
__global__ __launch_bounds__(256) void wp_att_kernel(const float* __restrict__ cpcat,
    const float* __restrict__ v_w, bf16_t* __restrict__ out) {
  int idx = blockIdx.x * 256 + threadIdx.x;  // 1048576
  int r1 = idx & 63;
  int cout = (idx >> 6) & 1023;
  int f = (idx >> 16) & 3;
  int lay = idx >> 18;
  const float* cp = cpcat + ((size_t)(lay * 4096 + r1 * 64)) * 12 + f;
  const float* vv = v_w + cout * 64;
  float acc = 0.f;
#pragma unroll 8
  for (int r2 = 0; r2 < 64; ++r2) acc += cp[r2 * 12] * vv[r2];
  out[idx] = (bf16_t)acc;
}

// Wp_fc1[l][j=g*1024+cout][r1] = sum_rr CPcat[l][r1][g*16+(rr>>2)][4+(rr&3)] * v_w[cout][rr]
__global__ __launch_bounds__(256) void wp_fc1_kernel(const float* __restrict__ cpcat,
    const float* __restrict__ v_w, bf16_t* __restrict__ out) {
  int idx = blockIdx.x * 256 + threadIdx.x;  // 1048576
  int r1 = idx & 63;
  int j = (idx >> 6) & 4095;
  int lay = idx >> 18;
  int g = j >> 10, cout = j & 1023;
  const float* cp = cpcat + ((size_t)(lay * 4096 + r1 * 64 + g * 16)) * 12 + 4;
  const float* vv = v_w + cout * 64;
  float acc = 0.f;
#pragma unroll 8
  for (int rr = 0; rr < 64; ++rr) acc += cp[(rr >> 2) * 12 + (rr & 3)] * vv[rr];
  out[idx] = (bf16_t)acc;
}

// Wp_fc2[l][cout][j] = sum_q CPcat[l][q][j>>2][8+(j&3)] * v_w[cout][q]
__global__ __launch_bounds__(256) void wp_fc2_kernel(const float* __restrict__ cpcat,
    const float* __restrict__ v_w, bf16_t* __restrict__ out) {
  int idx = blockIdx.x * 256 + threadIdx.x;  // 1048576
  int j = idx & 255;
  int cout = (idx >> 8) & 1023;
  int lay = idx >> 18;
  const float* cp = cpcat + ((size_t)(lay * 4096 + (j >> 2))) * 12 + 8 + (j & 3);
  const float* vv = v_w + cout * 64;
  float acc = 0.f;
#pragma unroll 8
  for (int q = 0; q < 64; ++q) acc += cp[(size_t)q * 768] * vv[q];
  out[idx] = (bf16_t)acc;
}

// LayerNorm over C=1024, write bf16
__global__ __launch_bounds__(256) void ln_kernel(const float* __restrict__ x,
    const float* __restrict__ g, const float* __restrict__ b, bf16_t* __restrict__ out) {
  int row = blockIdx.x;
  int t = threadIdx.x;
  const float4 v = ((const float4*)(x + (size_t)row * 1024))[t];
  float s = v.x + v.y + v.z + v.w;
  float s2 = v.x * v.x + v.y * v.y + v.z * v.z + v.w * v.w;
#pragma unroll
  for (int off = 32; off > 0; off >>= 1) {
    s += __shfl_down(s, off, 64);
    s2 += __shfl_down(s2, off, 64);
  }
  __shared__ float red[8];
  int wv = t >> 6;
  if ((t & 63) == 0) { red[wv * 2] = s; red[wv * 2 + 1] = s2; }
  __syncthreads();
  s = red[0] + red[2] + red[4] + red[6];
  s2 = red[1] + red[3] + red[5] + red[7];
  float mean = s * (1.0f / 1024.0f);
  float var = s2 * (1.0f / 1024.0f) - mean * mean;
  float rstd = rsqrtf(var + 1e-5f);
  const float4 gg = ((const float4*)g)[t];
  const float4 bb = ((const float4*)b)[t];
  union { bf16_t o[4]; uint2 u; } pk;
  pk.o[0] = (bf16_t)((v.x - mean) * rstd * gg.x + bb.x);
  pk.o[1] = (bf16_t)((v.y - mean) * rstd * gg.y + bb.y);
  pk.o[2] = (bf16_t)((v.z - mean) * rstd * gg.z + bb.z);
  pk.o[3] = (bf16_t)((v.w - mean) * rstd * gg.w + bb.w);
  *(uint2*)(out + (size_t)row * 1024 + t * 4) = pk.u;
}

// ---------------- generic bf16 GEMM: C = A[M,K] @ W[N,K]^T ----------------
// 128x128 tile, BK=64, 4 waves (each 64x64), global_load_lds(16B) staging with
// XOR-swizzled LDS (T2), m97 2-barrier K-loop. Templated epilogue.

enum { M_BF16 = 0, M_F32 = 1, M_QKV = 2, M_PROJ = 3, M_FC1 = 4, M_FC2 = 5 };

template <int MODE>
__global__ __launch_bounds__(256, 2)
void gemm_bt(const bf16_t* __restrict__ A, int lda,
             const bf16_t* __restrict__ W, int ldw,
             int N, int K, int ldc,
             bf16_t* __restrict__ bout, float* __restrict__ fout,
             const float* __restrict__ bias,
             const float* __restrict__ addbuf, int ldadd,
             float* __restrict__ resid,
             bf16_t* __restrict__ qout, bf16_t* __restrict__ kout, bf16_t* __restrict__ vout) {
  __shared__ __align__(16) bf16_t Al[128 * 64];
  __shared__ __align__(16) bf16_t Bl[128 * 64];
  int tid = threadIdx.x;
  int w = tid >> 6, l = tid & 63;
  int lr = l & 15, lh = l >> 4;
  int wr = w >> 1, wc = w & 1;
  int m0 = blockIdx.x * 128, n0 = blockIdx.y * 128;
  f32x4 acc[4][4];
  const f32x4 fz = {0.f, 0.f, 0.f, 0.f};
#pragma unroll
  for (int i = 0; i < 4; ++i)
#pragma unroll
    for (int j = 0; j < 4; ++j) acc[i][j] = fz;

  int srow = l >> 3;                          // row within 8-row chunk
  int scol = ((l & 7) << 4) ^ (srow << 4);    // pre-swizzled source byte col (T2, via m173)

  for (int k0 = 0; k0 < K; k0 += 64) {
#pragma unroll
    for (int c = 0; c < 8; ++c) {
      int chunk = w * 8 + c;
      if (chunk < 16) {
        int row = m0 + chunk * 8 + srow;
        async16((const char*)(A + (size_t)row * lda + k0) + scol, (char*)Al + chunk * 1024);
      } else {
        int ch = chunk - 16;
        int row = n0 + ch * 8 + srow;
        if (row >= N) row = N - 1;  // edge tiles (N=64): read valid mem, results discarded
        async16((const char*)(W + (size_t)row * ldw + k0) + scol, (char*)Bl + ch * 1024);
      }
    }
    __syncthreads();
#pragma unroll
    for (int kk = 0; kk < 2; ++kk) {
      bf16x8 af[4], bfv[4];
#pragma unroll
      for (int i = 0; i < 4; ++i) {
        int ar = wr * 64 + i * 16 + lr;
        af[i] = *(const bf16x8*)((const char*)Al + ar * 128 + (((lh << 4) + (kk << 6)) ^ ((ar & 7) << 4)));
        int br = wc * 64 + i * 16 + lr;
        bfv[i] = *(const bf16x8*)((const char*)Bl + br * 128 + (((lh << 4) + (kk << 6)) ^ ((br & 7) << 4)));
      }
#pragma unroll
      for (int i = 0; i < 4; ++i)
#pragma unroll
        for (int j = 0; j < 4; ++j) acc[i][j] = mfma16(af[i], bfv[j], acc[i][j]);
    }
    __syncthreads();
  }

  // epilogue — C/D layout: col = lane&15, row = (lane>>4)*4 + reg  [m89]
#pragma unroll
  for (int i = 0; i < 4; ++i) {
    int row0 = m0 + wr * 64 + i * 16 + lh * 4;
#pragma unroll
    for (int j = 0; j < 4; ++j) {
      int col = n0 + wc * 64 + j * 16 + lr;
      if (col < N) {
#pragma unroll
        for (int r = 0; r < 4; ++r) {
          int rr = row0 + r;
          float v = acc[i][j][r];
          if constexpr (MODE == M_BF16) {
            bout[(size_t)rr * ldc + col] = (bf16_t)v;
          } else if constexpr (MODE == M_F32) {
            fout[(size_t)rr * ldc + col] = v;
          } else if constexpr (MODE == M_QKV) {
            v += addbuf[(size_t)rr * ldadd + col];
            int which = col >> 10, crem = col & 1023;
            int hh = crem >> 6, dd = crem & 63;
            int bb = rr >> 10, nn = rr & 1023;
            size_t di = ((size_t)(bb * 16 + hh) * 1024 + nn) * 64 + dd;
            if (which == 0) qout[di] = (bf16_t)(v * 0.125f);  // q pre-scaled by D^-0.5
            else if (which == 1) kout[di] = (bf16_t)v;
            else vout[di] = (bf16_t)v;
          } else if constexpr (MODE == M_PROJ || MODE == M_FC2) {
            v += bias[col] + addbuf[(size_t)rr * ldadd + col];
            size_t xi = (size_t)rr * 1024 + col;
            v += resid[xi];
            resid[xi] = v;
          } else if constexpr (MODE == M_FC1) {
            v += bias[col] + addbuf[(size_t)rr * ldadd + col];
            bout[(size_t)rr * ldc + col] = (bf16_t)gelu_f(v);
          }
        }
      }
    }
  }
}

// ---------------- flash attention (causal), bf16 MFMA ----------------
// grid (N/64, B*H); 4 waves, each 16 q-rows; KV tiles of 64; K & V^T staged in
// XOR-swizzled LDS; P round-trips via padded per-wave LDS (stride 72 elems).

__global__ __launch_bounds__(256, 2)
void attn_kernel(const bf16_t* __restrict__ qb, const bf16_t* __restrict__ kb,
                 const bf16_t* __restrict__ vb, bf16_t* __restrict__ out) {
  __shared__ __align__(16) bf16_t Kl[64 * 64];
  __shared__ __align__(16) bf16_t Vl[64 * 64];      // V transposed: [d][key]
  __shared__ __align__(16) bf16_t Pl[4][16 * 72];
  int tid = threadIdx.x;
  int w = tid >> 6, l = tid & 63;
  int lr = l & 15, lh = l >> 4;
  int bh = blockIdx.y;
  int q0 = blockIdx.x * 64;
  const size_t base = (size_t)bh * 1024 * 64;

  const bf16_t* qrow_ptr = qb + base + (size_t)(q0 + w * 16 + lr) * 64;
  bf16x8 qf0 = *(const bf16x8*)(qrow_ptr + lh * 8);
  bf16x8 qf1 = *(const bf16x8*)(qrow_ptr + 32 + lh * 8);

  f32x4 acc_o[4];
  float m_run[4], l_run[4];
  const f32x4 fz = {0.f, 0.f, 0.f, 0.f};
#pragma unroll
  for (int i = 0; i < 4; ++i) { acc_o[i] = fz; m_run[i] = -1e30f; l_run[i] = 0.f; }

  int nt = blockIdx.x + 1;
  int srow = tid >> 2, sseg = tid & 3;

  for (int t = 0; t < nt; ++t) {
    int k0 = t * 64;
    __syncthreads();
    {  // stage K tile [key][d] (swizzled) and V^T tile [d][key] (swizzled)
      const bf16_t* ksrc = kb + base + (size_t)(k0 + srow) * 64 + sseg * 16;
      uint4 v0 = *(const uint4*)(ksrc);
      uint4 v1 = *(const uint4*)(ksrc + 8);
      int c0 = sseg * 32;
      *(uint4*)((char*)Kl + srow * 128 + (c0 ^ ((srow & 7) << 4))) = v0;
      *(uint4*)((char*)Kl + srow * 128 + ((c0 + 16) ^ ((srow & 7) << 4))) = v1;
      const bf16_t* vsrc = vb + base + (size_t)(k0 + srow) * 64 + sseg * 16;
      union { uint4 u[2]; bf16_t e[16]; } tv;
      tv.u[0] = *(const uint4*)(vsrc);
      tv.u[1] = *(const uint4*)(vsrc + 8);
#pragma unroll
      for (int j = 0; j < 16; ++j) {
        int d = sseg * 16 + j;
        *(bf16_t*)((char*)Vl + d * 128 + ((srow * 2) ^ ((d & 7) << 4))) = tv.e[j];
      }
    }
    __syncthreads();

    // S = Q K^T  (16q x 64keys per wave)
    f32x4 s[4];
#pragma unroll
    for (int kg = 0; kg < 4; ++kg) {
      int krow = kg * 16 + lr;
      const char* kbase = (const char*)Kl + krow * 128;
      int sw = (krow & 7) << 4;
      bf16x8 k0f = *(const bf16x8*)(kbase + ((lh * 16) ^ sw));
      bf16x8 k1f = *(const bf16x8*)(kbase + ((lh * 16 + 64) ^ sw));
      f32x4 z = fz;
      z = mfma16(qf0, k0f, z);
      z = mfma16(qf1, k1f, z);
      s[kg] = z;
    }

    // causal mask + online softmax (rows spread over 16-lane groups)
#pragma unroll
    for (int r = 0; r < 4; ++r) {
      int qrow = q0 + w * 16 + lh * 4 + r;
#pragma unroll
      for (int kg = 0; kg < 4; ++kg) {
        int key = k0 + kg * 16 + lr;
        if (key > qrow) s[kg][r] = -1e30f;
      }
      float mx = fmaxf(fmaxf(s[0][r], s[1][r]), fmaxf(s[2][r], s[3][r]));
      mx = fmaxf(mx, __shfl_xor(mx, 1, 64));
      mx = fmaxf(mx, __shfl_xor(mx, 2, 64));
      mx = fmaxf(mx, __shfl_xor(mx, 4, 64));
      mx = fmaxf(mx, __shfl_xor(mx, 8, 64));
      float mn = fmaxf(m_run[r], mx);
      float al = __expf(m_run[r] - mn);
      m_run[r] = mn;
      float sum = 0.f;
#pragma unroll
      for (int kg = 0; kg < 4; ++kg) {
        float pv = __expf(s[kg][r] - mn);
        s[kg][r] = pv;
        sum += pv;
      }
      sum += __shfl_xor(sum, 1, 64);
      sum += __shfl_xor(sum, 2, 64);
      sum += __shfl_xor(sum, 4, 64);
      sum += __shfl_xor(sum, 8, 64);
      l_run[r] = l_run[r] * al + sum;
#pragma unroll
      for (int dg = 0; dg < 4; ++dg) acc_o[dg][r] *= al;
#pragma unroll
      for (int kg = 0; kg < 4; ++kg)
        Pl[w][(lh * 4 + r) * 72 + kg * 16 + lr] = (bf16_t)s[kg][r];
    }

    // barrier: P rows are read by different lanes than wrote them (same wave,
    // but don't rely on compiler waitcnt ordering for cross-lane LDS reuse)
    __syncthreads();

    // O += P V
#pragma unroll
    for (int dg = 0; dg < 4; ++dg) {
      int vrow = dg * 16 + lr;
      const char* vbase = (const char*)Vl + vrow * 128;
      int sw = (vrow & 7) << 4;
#pragma unroll
      for (int kb2 = 0; kb2 < 2; ++kb2) {
        bf16x8 pf = *(const bf16x8*)(&Pl[w][lr * 72 + lh * 8 + kb2 * 32]);
        bf16x8 vf = *(const bf16x8*)(vbase + ((lh * 16 + kb2 * 64) ^ sw));
        acc_o[dg] = mfma16(pf, vf, acc_o[dg]);
      }
    }
  }

  int b = bh >> 4, h = bh & 15;
#pragma unroll
  for (int dg = 0; dg < 4; ++dg) {
    int col = h * 64 + dg * 16 + lr;
#pragma unroll
    for (int r = 0; r < 4; ++r) {
      int n = q0 + w * 16 + lh * 4 + r;
      out[((size_t)b * 1024 + n) * 1024 + col] = (bf16_t)(acc_o[dg][r] / l_run[r]);
    }
  }
}

// ---------------- host ----------------

template <int MODE>
static inline void gl(hipStream_t st, int N, const bf16_t* A, int lda, const bf16_t* W, int ldw,
                      int K, int ldc, bf16_t* bout, float* fout, const float* bias,
                      const float* addbuf, int ldadd, float* resid,
                      bf16_t* qo = nullptr, bf16_t* ko = nullptr, bf16_t* vo = nullptr) {
  gemm_bt<MODE><<<dim3(16, (N + 127) / 128), 256, 0, st>>>(A, lda, W, ldw, N, K, ldc, bout, fout,
                                                           bias, addbuf, ldadd, resid, qo, ko, vo);
}

extern "C" void kernel_launch(void* const* d_in, const int* in_sizes, int n_in,
                              void* d_out, int out_size, void* d_ws, size_t ws_size,
                              hipStream_t stream) {
  const float* x_in   = (const float*)d_in[0];
  const float* ln1_g  = (const float*)d_in[2];
  const float* ln1_b  = (const float*)d_in[3];
  const float* qkv_w  = (const float*)d_in[4];
  const float* proj_w = (const float*)d_in[5];
  const float* proj_b = (const float*)d_in[6];
  const float* cp_att = (const float*)d_in[7];
  const float* ln2_g  = (const float*)d_in[8];
  const float* ln2_b  = (const float*)d_in[9];
  const float* fc1_w  = (const float*)d_in[10];
  const float* fc1_b  = (const float*)d_in[11];
  const float* fc2_w  = (const float*)d_in[12];
  const float* fc2_b  = (const float*)d_in[13];
  const float* mlp_cp = (const float*)d_in[14];
  const float* u_w    = (const float*)d_in[15];
  const float* v_w    = (const float*)d_in[16];
  const float* cp_c   = (const float*)d_in[17];
  float* xbuf = (float*)d_out;  // running residual stream

  char* p = (char*)d_ws;
  auto carve = [&](size_t bytes) { char* r = p; p += (bytes + 255) & ~(size_t)255; return r; };
  bf16_t* wl    = (bf16_t*)carve(12582912ull * 2);  // per-layer bf16 weights (reused)
  bf16_t* uw_bf = (bf16_t*)carve(65536ull * 2);
  float*  cpcat = (float*) carve(196608ull * 4);
  bf16_t* wpatt = (bf16_t*)carve(1048576ull * 2);   // [L][4][1024][64]
  bf16_t* wpfc1 = (bf16_t*)carve(1048576ull * 2);   // [L][4096][64]
  bf16_t* wpfc2 = (bf16_t*)carve(1048576ull * 2);   // [L][1024][256]
  bf16_t* hbuf  = (bf16_t*)carve(2097152ull * 2);
  bf16_t* ubuf  = (bf16_t*)carve(131072ull * 2);
  bf16_t* u4buf = (bf16_t*)carve(524288ull * 2);
  float*  adapt = (float*) carve(8388608ull * 4);   // shared fp32 adapter scratch
  bf16_t* qbuf  = (bf16_t*)carve(2097152ull * 2);
  bf16_t* kbuf  = (bf16_t*)carve(2097152ull * 2);
  bf16_t* vbuf  = (bf16_t*)carve(2097152ull * 2);
  bf16_t* aout  = (bf16_t*)carve(2097152ull * 2);
  bf16_t* abuf  = (bf16_t*)carve(8388608ull * 2);

  hipMemcpyAsync(xbuf, x_in, (size_t)2048 * 1024 * 4, hipMemcpyDeviceToDevice, stream);
  convert_kernel<<<64, 256, 0, stream>>>(u_w, uw_bf, 16384);
  cpcat_kernel<<<64, 256, 0, stream>>>(cp_c, cp_att, mlp_cp, cpcat);
  wp_att_kernel<<<4096, 256, 0, stream>>>(cpcat, v_w, wpatt);
  wp_fc1_kernel<<<4096, 256, 0, stream>>>(cpcat, v_w, wpfc1);
  wp_fc2_kernel<<<4096, 256, 0, stream>>>(cpcat, v_w, wpfc2);

  for (int l = 0; l < 4; ++l) {
    convert_w_kernel<<<12288, 256, 0, stream>>>(qkv_w + (size_t)l * 3145728,
                                                proj_w + (size_t)l * 1048576,
                                                fc1_w + (size_t)l * 4194304,
                                                fc2_w + (size_t)l * 4194304, wl);
    bf16_t* wqkv  = wl;
    bf16_t* wproj = wl + 3145728;
    bf16_t* wfc1  = wl + 4194304;
    bf16_t* wfc2  = wl + 8388608;

    // ---- attention block ----
    ln_kernel<<<2048, 256, 0, stream>>>(xbuf, ln1_g + l * 1024, ln1_b + l * 1024, hbuf);
    gl<M_BF16>(stream, 64, hbuf, 1024, uw_bf, 1024, 1024, 64, ubuf, nullptr, nullptr, nullptr, 0, nullptr);
    gl<M_F32>(stream, 3072, ubuf, 64, wpatt + l * 262144, 64, 64, 3072, nullptr, adapt, nullptr, nullptr, 0, nullptr);
    gl<M_QKV>(stream, 3072, hbuf, 1024, wqkv, 1024, 1024, 0, nullptr, nullptr, nullptr, adapt, 3072, nullptr,
              qbuf, kbuf, vbuf);
    attn_kernel<<<dim3(16, 32), 256, 0, stream>>>(qbuf, kbuf, vbuf, aout);
    gl<M_BF16>(stream, 64, aout, 1024, uw_bf, 1024, 1024, 64, ubuf, nullptr, nullptr, nullptr, 0, nullptr);
    gl<M_F32>(stream, 1024, ubuf, 64, wpatt + l * 262144 + 196608, 64, 64, 1024, nullptr, adapt, nullptr, nullptr, 0, nullptr);
    gl<M_PROJ>(stream, 1024, aout, 1024, wproj, 1024, 1024, 0, nullptr, nullptr, proj_b + l * 1024, adapt, 1024, xbuf);

    // ---- ffn block ----
    ln_kernel<<<2048, 256, 0, stream>>>(xbuf, ln2_g + l * 1024, ln2_b + l * 1024, hbuf);
    gl<M_BF16>(stream, 64, hbuf, 1024, uw_bf, 1024, 1024, 64, ubuf, nullptr, nullptr, nullptr, 0, nullptr);
    gl<M_F32>(stream, 4096, ubuf, 64, wpfc1 + l * 262144, 64, 64, 4096, nullptr, adapt, nullptr, nullptr, 0, nullptr);
    gl<M_FC1>(stream, 4096, hbuf, 1024, wfc1, 1024, 1024, 4096, abuf, nullptr, fc1_b + l * 4096, adapt, 4096, nullptr);
    for (int g = 0; g < 4; ++g)
      gl<M_BF16>(stream, 64, abuf + g * 1024, 4096, uw_bf, 1024, 1024, 256, u4buf + g * 64, nullptr, nullptr, nullptr, 0, nullptr);
    gl<M_F32>(stream, 1024, u4buf, 256, wpfc2 + l * 262144, 256, 256, 1024, nullptr, adapt, nullptr, nullptr, 0, nullptr);
    gl<M_FC2>(stream, 1024, abuf, 4096, wfc2, 4096, 4096, 0, nullptr, nullptr, fc2_b + l * 1024, adapt, 1024, xbuf);
  }
}

// Round 5
// 1193.927 us; speedup vs baseline: 1.6907x; 1.6907x over previous
//
#include <hip/hip_runtime.h>
#include <cstdint>
#include <cstddef>

// CP_TransformerDecoder on MI355X — round 3 resubmit #2 (GPU acquisition
// timeouts x2). Adapter-fold restructure. All CP adapters are rank-64 weight
// updates: W_eff = W + u_w^T @ P, so each layer runs exactly: prep(4 K=64
// GEMMs) -> LN -> qkv -> attn -> proj -> LN -> fc1(+GELU) -> fc2. The
// latency-bound wp_* precompute kernels are LDS-tiled (were 128us each).

typedef __bf16 bf16_t;
typedef __bf16 bf16x8 __attribute__((ext_vector_type(8)));
typedef float  f32x4  __attribute__((ext_vector_type(4)));

#define DEVI __device__ __forceinline__

DEVI f32x4 mfma16(bf16x8 a, bf16x8 b, f32x4 c) {
  return __builtin_amdgcn_mfma_f32_16x16x32_bf16(a, b, c, 0, 0, 0);
}

DEVI void async16(const void* g, void* l) {
  __builtin_amdgcn_global_load_lds((const __attribute__((address_space(1))) void*)g,
                                   (__attribute__((address_space(3))) void*)l, 16, 0, 0);
}

DEVI float gelu_f(float v) { return 0.5f * v * (1.0f + erff(v * 0.70710678118654752440f)); }

// ---------------- preprocessing ----------------

// u_wT[c][r] = u_w[r][c]  (bf16), LDS-tiled transpose
__global__ __launch_bounds__(256) void utrans_kernel(const float* __restrict__ u_w,
                                                     bf16_t* __restrict__ out) {
  __shared__ float T[64][65];
  int t = threadIdx.x, c0 = blockIdx.x * 64;
#pragma unroll
  for (int i = 0; i < 16; ++i) {
    int idx = i * 256 + t;
    int r = idx >> 6, c = idx & 63;
    T[r][c] = u_w[r * 1024 + c0 + c];
  }
  __syncthreads();
#pragma unroll
  for (int i = 0; i < 16; ++i) {
    int idx = i * 256 + t;
    int c = idx >> 6, r = idx & 63;
    out[(size_t)(c0 + c) * 64 + r] = (bf16_t)T[r][c];
  }
}

// CPcat[l][r1][r2][f], f=0..3 from cp_att, f=4..11 from mlp_cp
__global__ __launch_bounds__(256) void cpcat_kernel(const float* __restrict__ cp_c,
    const float* __restrict__ cp_att, const float* __restrict__ mlp_cp, float* __restrict__ cpcat) {
  int idx = blockIdx.x * 256 + threadIdx.x;  // 16384 = L*64*64
  int lay = idx >> 12, ab = idx & 4095;
  const float* crow = cp_c + (size_t)ab * 64;
  float acc[12];
#pragma unroll
  for (int f = 0; f < 12; ++f) acc[f] = 0.f;
  for (int r = 0; r < 64; ++r) {
    float cv = crow[r];
    const float* wa = cp_att + lay * 256 + r * 4;
    const float* wm = mlp_cp + lay * 512 + r * 8;
#pragma unroll
    for (int f = 0; f < 4; ++f) acc[f] += cv * wa[f];
#pragma unroll
    for (int f = 0; f < 8; ++f) acc[4 + f] += cv * wm[f];
  }
  float* o = cpcat + (size_t)idx * 12;
#pragma unroll
  for (int f = 0; f < 12; ++f) o[f] = acc[f];
}

// wpatt[l][f][cout][r1] = sum_r2 CPcat[l][r1][r2][f] * v_w[cout][r2]
// block: (lay, f, 128-cout chunk); slab ST[r2][r1] in LDS (padded)
__global__ __launch_bounds__(256) void wp_att_kernel(const float* __restrict__ cpcat,
    const float* __restrict__ v_w, bf16_t* __restrict__ out) {
  __shared__ float ST[64][65];
  int lay = blockIdx.y;
  int f = blockIdx.x >> 3, cc = blockIdx.x & 7;
  int t = threadIdx.x;
#pragma unroll
  for (int i = 0; i < 16; ++i) {
    int idx = i * 256 + t;
    int r1 = idx >> 6, r2 = idx & 63;
    ST[r2][r1] = cpcat[(size_t)(lay * 4096 + r1 * 64 + r2) * 12 + f];
  }
  __syncthreads();
  int lane = t & 63, grp = t >> 6;
  for (int ii = 0; ii < 32; ii += 4) {
    int cb = cc * 128 + grp * 32 + ii;
    const float* v0 = v_w + (size_t)cb * 64;
    const float* v1 = v0 + 64;
    const float* v2 = v0 + 128;
    const float* v3 = v0 + 192;
    float a0 = 0.f, a1 = 0.f, a2 = 0.f, a3 = 0.f;
#pragma unroll 8
    for (int r2 = 0; r2 < 64; ++r2) {
      float sv = ST[r2][lane];
      a0 += sv * v0[r2]; a1 += sv * v1[r2]; a2 += sv * v2[r2]; a3 += sv * v3[r2];
    }
    size_t ob = ((size_t)(lay * 4 + f) * 1024 + cb) * 64 + lane;
    out[ob] = (bf16_t)a0; out[ob + 64] = (bf16_t)a1;
    out[ob + 128] = (bf16_t)a2; out[ob + 192] = (bf16_t)a3;
  }
}

// wpfc1[l][g*1024+cout][r1] = sum_rr CPcat[l][r1][g*16+(rr>>2)][4+(rr&3)] * v_w[cout][rr]
__global__ __launch_bounds__(256) void wp_fc1_kernel(const float* __restrict__ cpcat,
    const float* __restrict__ v_w, bf16_t* __restrict__ out) {
  __shared__ float ST[64][65];
  int lay = blockIdx.y;
  int g = blockIdx.x >> 3, cc = blockIdx.x & 7;
  int t = threadIdx.x;
#pragma unroll
  for (int i = 0; i < 16; ++i) {
    int idx = i * 256 + t;
    int r1 = idx >> 6, rr = idx & 63;
    ST[rr][r1] = cpcat[(size_t)(lay * 4096 + r1 * 64 + g * 16 + (rr >> 2)) * 12 + 4 + (rr & 3)];
  }
  __syncthreads();
  int lane = t & 63, grp = t >> 6;
  for (int ii = 0; ii < 32; ii += 4) {
    int cb = cc * 128 + grp * 32 + ii;
    const float* v0 = v_w + (size_t)cb * 64;
    const float* v1 = v0 + 64;
    const float* v2 = v0 + 128;
    const float* v3 = v0 + 192;
    float a0 = 0.f, a1 = 0.f, a2 = 0.f, a3 = 0.f;
#pragma unroll 8
    for (int rr = 0; rr < 64; ++rr) {
      float sv = ST[rr][lane];
      a0 += sv * v0[rr]; a1 += sv * v1[rr]; a2 += sv * v2[rr]; a3 += sv * v3[rr];
    }
    size_t ob = ((size_t)lay * 4096 + g * 1024 + cb) * 64 + lane;
    out[ob] = (bf16_t)a0; out[ob + 64] = (bf16_t)a1;
    out[ob + 128] = (bf16_t)a2; out[ob + 192] = (bf16_t)a3;
  }
}

// wpfc2[l][cout][jj] = sum_q CPcat[l][q][jj>>2][8+(jj&3)] * v_w[cout][q]
// block: (lay, jj-chunk 64, cout-chunk 128); slab SJ[q][j64]
__global__ __launch_bounds__(256) void wp_fc2_kernel(const float* __restrict__ cpcat,
    const float* __restrict__ v_w, bf16_t* __restrict__ out) {
  __shared__ float SJ[64][65];
  int lay = blockIdx.y;
  int jc = blockIdx.x >> 3, cc = blockIdx.x & 7;
  int t = threadIdx.x;
#pragma unroll
  for (int i = 0; i < 16; ++i) {
    int idx = i * 256 + t;
    int q = idx >> 6, j64 = idx & 63;
    SJ[q][j64] = cpcat[(size_t)(lay * 4096 + q * 64 + jc * 16 + (j64 >> 2)) * 12 + 8 + (j64 & 3)];
  }
  __syncthreads();
  int lane = t & 63, grp = t >> 6;
  for (int ii = 0; ii < 32; ii += 4) {
    int cb = cc * 128 + grp * 32 + ii;
    const float* v0 = v_w + (size_t)cb * 64;
    const float* v1 = v0 + 64;
    const float* v2 = v0 + 128;
    const float* v3 = v0 + 192;
    float a0 = 0.f, a1 = 0.f, a2 = 0.f, a3 = 0.f;
#pragma unroll 8
    for (int q = 0; q < 64; ++q) {
      float sv = SJ[q][lane];
      a0 += sv * v0[q]; a1 += sv * v1[q]; a2 += sv * v2[q]; a3 += sv * v3[q];
    }
    size_t ob = ((size_t)lay * 1024 + cb) * 256 + jc * 64 + lane;
    out[ob] = (bf16_t)a0; out[ob + 256] = (bf16_t)a1;
    out[ob + 512] = (bf16_t)a2; out[ob + 768] = (bf16_t)a3;
  }
}

// LayerNorm over C=1024, write bf16
__global__ __launch_bounds__(256) void ln_kernel(const float* __restrict__ x,
    const float* __restrict__ g, const float* __restrict__ b, bf16_t* __restrict__ out) {
  int row = blockIdx.x;
  int t = threadIdx.x;
  const float4 v = ((const float4*)(x + (size_t)row * 1024))[t];
  float s = v.x + v.y + v.z + v.w;
  float s2 = v.x * v.x + v.y * v.y + v.z * v.z + v.w * v.w;
#pragma unroll
  for (int off = 32; off > 0; off >>= 1) {
    s += __shfl_down(s, off, 64);
    s2 += __shfl_down(s2, off, 64);
  }
  __shared__ float red[8];
  int wv = t >> 6;
  if ((t & 63) == 0) { red[wv * 2] = s; red[wv * 2 + 1] = s2; }
  __syncthreads();
  s = red[0] + red[2] + red[4] + red[6];
  s2 = red[1] + red[3] + red[5] + red[7];
  float mean = s * (1.0f / 1024.0f);
  float var = s2 * (1.0f / 1024.0f) - mean * mean;
  float rstd = rsqrtf(var + 1e-5f);
  const float4 gg = ((const float4*)g)[t];
  const float4 bb = ((const float4*)b)[t];
  union { bf16_t o[4]; uint2 u; } pk;
  pk.o[0] = (bf16_t)((v.x - mean) * rstd * gg.x + bb.x);
  pk.o[1] = (bf16_t)((v.y - mean) * rstd * gg.y + bb.y);
  pk.o[2] = (bf16_t)((v.z - mean) * rstd * gg.z + bb.z);
  pk.o[3] = (bf16_t)((v.w - mean) * rstd * gg.w + bb.w);
  *(uint2*)(out + (size_t)row * 1024 + t * 4) = pk.u;
}

// ---------------- generic bf16 GEMM: C = A[M,K] @ W[N,K]^T ----------------
// 128x128 tile, BK=64, 4 waves (each 64x64), global_load_lds(16B) staging with
// XOR-swizzled LDS (T2), m97 2-barrier K-loop. Templated epilogue.
// M_PREP: out_bf16[rr][col+z*cz] = mfma + wadd_f32  (weight fold, grid.z slices)
// M_QKV : scatter to q/k/v [B,H,N,D], q pre-scaled
// M_RESID: + bias + resid (f32 residual stream, in-place)
// M_FC1 : + bias, GELU, bf16 out

enum { M_PREP = 0, M_QKV = 1, M_RESID = 2, M_FC1 = 3 };

template <int MODE>
__global__ __launch_bounds__(256, 2)
void gemm_bt(const bf16_t* __restrict__ A, int lda,
             const bf16_t* __restrict__ W, int ldw,
             int N, int K, int ldc,
             bf16_t* __restrict__ bout,
             const float* __restrict__ bias,
             const float* __restrict__ wadd, int ldadd,
             float* __restrict__ resid,
             bf16_t* __restrict__ qout, bf16_t* __restrict__ kout, bf16_t* __restrict__ vout,
             int az, int cz) {
  __shared__ __align__(16) bf16_t Al[128 * 64];
  __shared__ __align__(16) bf16_t Bl[128 * 64];
  int tid = threadIdx.x;
  int w = tid >> 6, l = tid & 63;
  int lr = l & 15, lh = l >> 4;
  int wr = w >> 1, wc = w & 1;
  int m0 = blockIdx.x * 128, n0 = blockIdx.y * 128;
  int zz = blockIdx.z;
  A += (size_t)zz * az;
  int zcol = zz * cz;
  f32x4 acc[4][4];
  const f32x4 fz = {0.f, 0.f, 0.f, 0.f};
#pragma unroll
  for (int i = 0; i < 4; ++i)
#pragma unroll
    for (int j = 0; j < 4; ++j) acc[i][j] = fz;

  int srow = l >> 3;                          // row within 8-row chunk
  int scol = ((l & 7) << 4) ^ (srow << 4);    // pre-swizzled source byte col (T2, via m173)

  for (int k0 = 0; k0 < K; k0 += 64) {
#pragma unroll
    for (int c = 0; c < 8; ++c) {
      int chunk = w * 8 + c;
      if (chunk < 16) {
        int row = m0 + chunk * 8 + srow;
        async16((const char*)(A + (size_t)row * lda + k0) + scol, (char*)Al + chunk * 1024);
      } else {
        int ch = chunk - 16;
        int row = n0 + ch * 8 + srow;
        async16((const char*)(W + (size_t)row * ldw + k0) + scol, (char*)Bl + ch * 1024);
      }
    }
    __syncthreads();
#pragma unroll
    for (int kk = 0; kk < 2; ++kk) {
      bf16x8 af[4], bfv[4];
#pragma unroll
      for (int i = 0; i < 4; ++i) {
        int ar = wr * 64 + i * 16 + lr;
        af[i] = *(const bf16x8*)((const char*)Al + ar * 128 + (((lh << 4) + (kk << 6)) ^ ((ar & 7) << 4)));
        int br = wc * 64 + i * 16 + lr;
        bfv[i] = *(const bf16x8*)((const char*)Bl + br * 128 + (((lh << 4) + (kk << 6)) ^ ((br & 7) << 4)));
      }
#pragma unroll
      for (int i = 0; i < 4; ++i)
#pragma unroll
        for (int j = 0; j < 4; ++j) acc[i][j] = mfma16(af[i], bfv[j], acc[i][j]);
    }
    __syncthreads();
  }

  // epilogue — C/D layout: col = lane&15, row = (lane>>4)*4 + reg  [m89]
#pragma unroll
  for (int i = 0; i < 4; ++i) {
    int row0 = m0 + wr * 64 + i * 16 + lh * 4;
#pragma unroll
    for (int j = 0; j < 4; ++j) {
      int col = n0 + wc * 64 + j * 16 + lr;
#pragma unroll
      for (int r = 0; r < 4; ++r) {
        int rr = row0 + r;
        float v = acc[i][j][r];
        if constexpr (MODE == M_PREP) {
          int colw = col + zcol;
          v += wadd[(size_t)rr * ldadd + colw];
          bout[(size_t)rr * ldc + colw] = (bf16_t)v;
        } else if constexpr (MODE == M_QKV) {
          int which = col >> 10, crem = col & 1023;
          int hh = crem >> 6, dd = crem & 63;
          int bb = rr >> 10, nn = rr & 1023;
          size_t di = ((size_t)(bb * 16 + hh) * 1024 + nn) * 64 + dd;
          if (which == 0) qout[di] = (bf16_t)(v * 0.125f);  // q pre-scaled by D^-0.5
          else if (which == 1) kout[di] = (bf16_t)v;
          else vout[di] = (bf16_t)v;
        } else if constexpr (MODE == M_RESID) {
          v += bias[col];
          size_t xi = (size_t)rr * 1024 + col;
          v += resid[xi];
          resid[xi] = v;
        } else if constexpr (MODE == M_FC1) {
          v += bias[col];
          bout[(size_t)rr * ldc + col] = (bf16_t)gelu_f(v);
        }
      }
    }
  }
}

// ---------------- flash attention (causal), bf16 MFMA ----------------
// grid (N/64, B*H); 4 waves, each 16 q-rows; KV tiles of 64; K & V^T staged in
// XOR-swizzled LDS; P round-trips via padded per-wave LDS (stride 72 elems).

__global__ __launch_bounds__(256, 2)
void attn_kernel(const bf16_t* __restrict__ qb, const bf16_t* __restrict__ kb,
                 const bf16_t* __restrict__ vb, bf16_t* __restrict__ out) {
  __shared__ __align__(16) bf16_t Kl[64 * 64];
  __shared__ __align__(16) bf16_t Vl[64 * 64];      // V transposed: [d][key]
  __shared__ __align__(16) bf16_t Pl[4][16 * 72];
  int tid = threadIdx.x;
  int w = tid >> 6, l = tid & 63;
  int lr = l & 15, lh = l >> 4;
  int bh = blockIdx.y;
  int q0 = blockIdx.x * 64;
  const size_t base = (size_t)bh * 1024 * 64;

  const bf16_t* qrow_ptr = qb + base + (size_t)(q0 + w * 16 + lr) * 64;
  bf16x8 qf0 = *(const bf16x8*)(qrow_ptr + lh * 8);
  bf16x8 qf1 = *(const bf16x8*)(qrow_ptr + 32 + lh * 8);

  f32x4 acc_o[4];
  float m_run[4], l_run[4];
  const f32x4 fz = {0.f, 0.f, 0.f, 0.f};
#pragma unroll
  for (int i = 0; i < 4; ++i) { acc_o[i] = fz; m_run[i] = -1e30f; l_run[i] = 0.f; }

  int nt = blockIdx.x + 1;
  int srow = tid >> 2, sseg = tid & 3;

  for (int t = 0; t < nt; ++t) {
    int k0 = t * 64;
    __syncthreads();
    {  // stage K tile [key][d] (swizzled) and V^T tile [d][key] (swizzled)
      const bf16_t* ksrc = kb + base + (size_t)(k0 + srow) * 64 + sseg * 16;
      uint4 v0 = *(const uint4*)(ksrc);
      uint4 v1 = *(const uint4*)(ksrc + 8);
      int c0 = sseg * 32;
      *(uint4*)((char*)Kl + srow * 128 + (c0 ^ ((srow & 7) << 4))) = v0;
      *(uint4*)((char*)Kl + srow * 128 + ((c0 + 16) ^ ((srow & 7) << 4))) = v1;
      const bf16_t* vsrc = vb + base + (size_t)(k0 + srow) * 64 + sseg * 16;
      union { uint4 u[2]; bf16_t e[16]; } tv;
      tv.u[0] = *(const uint4*)(vsrc);
      tv.u[1] = *(const uint4*)(vsrc + 8);
#pragma unroll
      for (int j = 0; j < 16; ++j) {
        int d = sseg * 16 + j;
        *(bf16_t*)((char*)Vl + d * 128 + ((srow * 2) ^ ((d & 7) << 4))) = tv.e[j];
      }
    }
    __syncthreads();

    // S = Q K^T  (16q x 64keys per wave)
    f32x4 s[4];
#pragma unroll
    for (int kg = 0; kg < 4; ++kg) {
      int krow = kg * 16 + lr;
      const char* kbase = (const char*)Kl + krow * 128;
      int sw = (krow & 7) << 4;
      bf16x8 k0f = *(const bf16x8*)(kbase + ((lh * 16) ^ sw));
      bf16x8 k1f = *(const bf16x8*)(kbase + ((lh * 16 + 64) ^ sw));
      f32x4 z = fz;
      z = mfma16(qf0, k0f, z);
      z = mfma16(qf1, k1f, z);
      s[kg] = z;
    }

    // causal mask + online softmax (rows spread over 16-lane groups)
#pragma unroll
    for (int r = 0; r < 4; ++r) {
      int qrow = q0 + w * 16 + lh * 4 + r;
#pragma unroll
      for (int kg = 0; kg < 4; ++kg) {
        int key = k0 + kg * 16 + lr;
        if (key > qrow) s[kg][r] = -1e30f;
      }
      float mx = fmaxf(fmaxf(s[0][r], s[1][r]), fmaxf(s[2][r], s[3][r]));
      mx = fmaxf(mx, __shfl_xor(mx, 1, 64));
      mx = fmaxf(mx, __shfl_xor(mx, 2, 64));
      mx = fmaxf(mx, __shfl_xor(mx, 4, 64));
      mx = fmaxf(mx, __shfl_xor(mx, 8, 64));
      float mn = fmaxf(m_run[r], mx);
      float al = __expf(m_run[r] - mn);
      m_run[r] = mn;
      float sum = 0.f;
#pragma unroll
      for (int kg = 0; kg < 4; ++kg) {
        float pv = __expf(s[kg][r] - mn);
        s[kg][r] = pv;
        sum += pv;
      }
      sum += __shfl_xor(sum, 1, 64);
      sum += __shfl_xor(sum, 2, 64);
      sum += __shfl_xor(sum, 4, 64);
      sum += __shfl_xor(sum, 8, 64);
      l_run[r] = l_run[r] * al + sum;
#pragma unroll
      for (int dg = 0; dg < 4; ++dg) acc_o[dg][r] *= al;
#pragma unroll
      for (int kg = 0; kg < 4; ++kg)
        Pl[w][(lh * 4 + r) * 72 + kg * 16 + lr] = (bf16_t)s[kg][r];
    }

    // barrier: P rows are read by different lanes than wrote them
    __syncthreads();

    // O += P V
#pragma unroll
    for (int dg = 0; dg < 4; ++dg) {
      int vrow = dg * 16 + lr;
      const char* vbase = (const char*)Vl + vrow * 128;
      int sw = (vrow & 7) << 4;
#pragma unroll
      for (int kb2 = 0; kb2 < 2; ++kb2) {
        bf16x8 pf = *(const bf16x8*)(&Pl[w][lr * 72 + lh * 8 + kb2 * 32]);
        bf16x8 vf = *(const bf16x8*)(vbase + ((lh * 16 + kb2 * 64) ^ sw));
        acc_o[dg] = mfma16(pf, vf, acc_o[dg]);
      }
    }
  }

  int b = bh >> 4, h = bh & 15;
#pragma unroll
  for (int dg = 0; dg < 4; ++dg) {
    int col = h * 64 + dg * 16 + lr;
#pragma unroll
    for (int r = 0; r < 4; ++r) {
      int n = q0 + w * 16 + lh * 4 + r;
      out[((size_t)b * 1024 + n) * 1024 + col] = (bf16_t)(acc_o[dg][r] / l_run[r]);
    }
  }
}

// ---------------- host ----------------

template <int MODE>
static inline void gl(hipStream_t st, int M, int N, int K,
                     const bf16_t* A, int lda, const bf16_t* W, int ldw, int ldc,
                     bf16_t* bout, const float* bias, const float* wadd, int ldadd,
                     float* resid,
                     bf16_t* qo = nullptr, bf16_t* ko = nullptr, bf16_t* vo = nullptr,
                     int az = 0, int cz = 0, int gz = 1) {
  gemm_bt<MODE><<<dim3(M / 128, N / 128, gz), 256, 0, st>>>(
      A, lda, W, ldw, N, K, ldc, bout, bias, wadd, ldadd, resid, qo, ko, vo, az, cz);
}

extern "C" void kernel_launch(void* const* d_in, const int* in_sizes, int n_in,
                              void* d_out, int out_size, void* d_ws, size_t ws_size,
                              hipStream_t stream) {
  const float* x_in   = (const float*)d_in[0];
  const float* ln1_g  = (const float*)d_in[2];
  const float* ln1_b  = (const float*)d_in[3];
  const float* qkv_w  = (const float*)d_in[4];
  const float* proj_w = (const float*)d_in[5];
  const float* proj_b = (const float*)d_in[6];
  const float* cp_att = (const float*)d_in[7];
  const float* ln2_g  = (const float*)d_in[8];
  const float* ln2_b  = (const float*)d_in[9];
  const float* fc1_w  = (const float*)d_in[10];
  const float* fc1_b  = (const float*)d_in[11];
  const float* fc2_w  = (const float*)d_in[12];
  const float* fc2_b  = (const float*)d_in[13];
  const float* mlp_cp = (const float*)d_in[14];
  const float* u_w    = (const float*)d_in[15];
  const float* v_w    = (const float*)d_in[16];
  const float* cp_c   = (const float*)d_in[17];
  float* xbuf = (float*)d_out;  // running residual stream

  char* p = (char*)d_ws;
  auto carve = [&](size_t bytes) { char* r = p; p += (bytes + 255) & ~(size_t)255; return r; };
  bf16_t* wl    = (bf16_t*)carve(12582912ull * 2);  // per-layer folded bf16 weights
  bf16_t* uwT   = (bf16_t*)carve(65536ull * 2);     // u_w^T [1024][64]
  float*  cpcat = (float*) carve(196608ull * 4);
  bf16_t* wpatt = (bf16_t*)carve(1048576ull * 2);   // [L][4][1024][64]
  bf16_t* wpfc1 = (bf16_t*)carve(1048576ull * 2);   // [L][4096][64]
  bf16_t* wpfc2 = (bf16_t*)carve(1048576ull * 2);   // [L][1024][256]
  bf16_t* hbuf  = (bf16_t*)carve(2097152ull * 2);
  bf16_t* qbuf  = (bf16_t*)carve(2097152ull * 2);
  bf16_t* kbuf  = (bf16_t*)carve(2097152ull * 2);
  bf16_t* vbuf  = (bf16_t*)carve(2097152ull * 2);
  bf16_t* aout  = (bf16_t*)carve(2097152ull * 2);
  bf16_t* abuf  = (bf16_t*)carve(8388608ull * 2);

  hipMemcpyAsync(xbuf, x_in, (size_t)2048 * 1024 * 4, hipMemcpyDeviceToDevice, stream);
  utrans_kernel<<<16, 256, 0, stream>>>(u_w, uwT);
  cpcat_kernel<<<64, 256, 0, stream>>>(cp_c, cp_att, mlp_cp, cpcat);
  wp_att_kernel<<<dim3(32, 4), 256, 0, stream>>>(cpcat, v_w, wpatt);
  wp_fc1_kernel<<<dim3(32, 4), 256, 0, stream>>>(cpcat, v_w, wpfc1);
  wp_fc2_kernel<<<dim3(32, 4), 256, 0, stream>>>(cpcat, v_w, wpfc2);

  for (int l = 0; l < 4; ++l) {
    bf16_t* wqkv  = wl;
    bf16_t* wproj = wl + 3145728;
    bf16_t* wfc1  = wl + 4194304;
    bf16_t* wfc2  = wl + 8388608;

    // ---- weight fold: W_eff = W + u_w^T @ P  (K=64 prep GEMMs) ----
    gl<M_PREP>(stream, 3072, 1024, 64, wpatt + (size_t)l * 262144, 64, uwT, 64, 1024,
               wqkv, nullptr, qkv_w + (size_t)l * 3145728, 1024, nullptr);
    gl<M_PREP>(stream, 1024, 1024, 64, wpatt + (size_t)l * 262144 + 196608, 64, uwT, 64, 1024,
               wproj, nullptr, proj_w + (size_t)l * 1048576, 1024, nullptr);
    gl<M_PREP>(stream, 4096, 1024, 64, wpfc1 + (size_t)l * 262144, 64, uwT, 64, 1024,
               wfc1, nullptr, fc1_w + (size_t)l * 4194304, 1024, nullptr);
    gl<M_PREP>(stream, 1024, 1024, 64, wpfc2 + (size_t)l * 262144, 256, uwT, 64, 4096,
               wfc2, nullptr, fc2_w + (size_t)l * 4194304, 4096, nullptr,
               nullptr, nullptr, nullptr, 64, 1024, 4);

    // ---- attention block ----
    ln_kernel<<<2048, 256, 0, stream>>>(xbuf, ln1_g + l * 1024, ln1_b + l * 1024, hbuf);
    gl<M_QKV>(stream, 2048, 3072, 1024, hbuf, 1024, wqkv, 1024, 0,
              nullptr, nullptr, nullptr, 0, nullptr, qbuf, kbuf, vbuf);
    attn_kernel<<<dim3(16, 32), 256, 0, stream>>>(qbuf, kbuf, vbuf, aout);
    gl<M_RESID>(stream, 2048, 1024, 1024, aout, 1024, wproj, 1024, 0,
                nullptr, proj_b + l * 1024, nullptr, 0, xbuf);

    // ---- ffn block ----
    ln_kernel<<<2048, 256, 0, stream>>>(xbuf, ln2_g + l * 1024, ln2_b + l * 1024, hbuf);
    gl<M_FC1>(stream, 2048, 4096, 1024, hbuf, 1024, wfc1, 1024, 4096,
              abuf, fc1_b + l * 4096, nullptr, 0, nullptr);
    gl<M_RESID>(stream, 2048, 1024, 4096, abuf, 4096, wfc2, 4096, 0,
                nullptr, fc2_b + l * 1024, nullptr, 0, xbuf);
  }
}